// Round 9
// baseline (46.057 us; speedup 1.0000x reference)
//
#include <hip/hip_runtime.h>
#include <cmath>

namespace {

typedef _Float16 h8 __attribute__((ext_vector_type(8)));

constexpr int C_     = 64;
constexpr int L_     = 32768;
constexpr int TILE   = 8192;
constexpr int HALO   = 776;           // receptive field 765, rounded to unit-8
constexpr int NB     = TILE + HALO;   // 8968 halfs
constexpr int NU     = NB / 8;        // 1121 h8 units
constexpr int HALO_U = HALO / 8;      // 97
constexpr int NT     = L_ / TILE;     // 4 tiles per row
constexpr int BLK    = 256;
constexpr int UMAX   = (NU + BLK - 1) / BLK;   // 5 unit-slots (last partial)

__device__ __forceinline__ h8 ld8(const _Float16* p) { return *reinterpret_cast<const h8*>(p); }
__device__ __forceinline__ void st8(_Float16* p, h8 v) { *reinterpret_cast<h8*>(p) = v; }
__device__ __forceinline__ float4 ld4f(const float* p) { return *reinterpret_cast<const float4*>(p); }
__device__ __forceinline__ void st4f(float* p, float4 v) { *reinterpret_cast<float4*>(p) = v; }
__device__ __forceinline__ h8 sp8(_Float16 v) { return (h8){v,v,v,v,v,v,v,v}; }

template<int K>
__device__ __forceinline__ h8 shconc(h8 A, h8 B) {
    return __builtin_shufflevector(A, B, K, K+1, K+2, K+3, K+4, K+5, K+6, K+7);
}

// tanh-form GELU: v * sigmoid(1.5958*v + 0.07135*v^3); absmax-verified vs the
// erf form across five rounds (identical 0.0078125 overall absmax).
__device__ __forceinline__ float gelu_f(float v) {
    const float z = v * (1.5957691216057308f + 0.0713548162726f * v * v);
    const float e = __expf(-z);
    return v * __builtin_amdgcn_rcpf(1.0f + e);
}

// Phase A of one level (dilation D): read taps from the SINGLE in-place buffer,
// accumulate y, compute new low into lw[] (registers only — no LDS write here).
// Caller then does: __syncthreads(); publish (phase B); __syncthreads().
// Frontier recursion (correctness-proven r3..r8): STARTU per level
// 1,2,4,7,13,25,49,97; a valid unit g at level D reads down to g-3D/8 which
// stays >= previous STARTU, so below-frontier garbage is never read and all
// tap indices are >= 0 (no clamping needed).
// Guards kept per-slot: they bound live ranges (r4-r7: unguarded variants
// hoisted 15 tap loads -> 188 VGPR or forced scratch demotion).
template<int D, int STARTU, bool LAST>
__device__ __forceinline__ void level_compute(const _Float16* __restrict__ buf,
                                              const float* h0f, const float* h1f,
                                              float wi, float w0,
                                              h8* lw, h8* yacc, int tid)
{
    _Float16 c1[4], c0[4];
#pragma unroll
    for (int t = 0; t < 4; ++t) {
        c1[t] = (_Float16)(wi * h1f[t]);
        c0[t] = (_Float16)(LAST ? w0 * h0f[t] : h0f[t]);
    }

#pragma unroll
    for (int u = 0; u < UMAX; ++u) {
        const int un = tid + u * BLK;
        if (un >= STARTU && un < NU) {
            const int p = 8 * un;
            const h8 T3 = lw[u];
            h8 T0, T1, T2;
            if constexpr (D == 1) {
                h8 Lv = ld8(&buf[p - 8]);
                T0 = shconc<5>(Lv, T3);
                T1 = shconc<6>(Lv, T3);
                T2 = shconc<7>(Lv, T3);
            } else if constexpr (D == 2) {
                h8 Lv = ld8(&buf[p - 8]);
                T0 = shconc<2>(Lv, T3);
                T1 = shconc<4>(Lv, T3);
                T2 = shconc<6>(Lv, T3);
            } else if constexpr (D == 4) {
                h8 Lv  = ld8(&buf[p - 8]);
                h8 LL  = ld8(&buf[p - 16]);
                T0 = shconc<4>(LL, Lv);
                T1 = Lv;
                T2 = shconc<4>(Lv, T3);
            } else {
                T0 = ld8(&buf[p - 3 * D]);
                T1 = ld8(&buf[p - 2 * D]);
                T2 = ld8(&buf[p - D]);
            }
            if (un >= HALO_U) {   // y only matters inside the output tile
                yacc[u] += sp8(c1[0]) * T0 + sp8(c1[1]) * T1
                         + sp8(c1[2]) * T2 + sp8(c1[3]) * T3;
            }
            h8 nl = sp8(c0[0]) * T0 + sp8(c0[1]) * T1
                  + sp8(c0[2]) * T2 + sp8(c0[3]) * T3;
            if constexpr (LAST) {
                yacc[u] += nl;          // c0 already folded with w0
            } else {
                lw[u] = nl;
            }
        }
    }
}

// Phase B: write the new level values in place.
template<int STARTU>
__device__ __forceinline__ void publish(_Float16* __restrict__ buf,
                                        const h8* lw, int tid)
{
#pragma unroll
    for (int u = 0; u < UMAX; ++u) {
        const int un = tid + u * BLK;
        if (un >= STARTU && un < NU) st8(&buf[8 * un], lw[u]);
    }
}

// min-waves=7 (VGPR cap 73): strictly safer than cap 64 — if actual pressure
// lands <=64 the HW still gives 8 blocks/CU (LDS 17936B -> 8 fit); if 65-73 we
// get 7. Caps BELOW pressure caused catastrophic scratch demotion (r4-r7).
__global__ __launch_bounds__(BLK, 7)
void cmrc_kernel(const float* __restrict__ x,
                 const float* __restrict__ h0,
                 const float* __restrict__ h1,
                 const float* __restrict__ w,
                 float* __restrict__ out)
{
    __shared__ alignas(16) _Float16 buf[NB];   // SINGLE in-place buffer, 17936 B

    const int tid  = threadIdx.x;
    const int blk  = blockIdx.x;
    const int tile = blk % NT;
    const int bc   = blk / NT;            // b*C + c
    const int c    = bc % C_;
    const long row = (long)bc * L_;
    const int  t0  = tile * TILE - HALO;  // global pos of buffer p=0

    float h0v[4], h1v[4];
#pragma unroll
    for (int k = 0; k < 4; ++k) { h0v[k] = h0[c*4+k]; h1v[k] = h1[c*4+k]; }
    float wv[10];
#pragma unroll
    for (int i = 0; i < 10; ++i) wv[i] = w[c*10+i];

    h8 lw[UMAX];     // running low residual (own units, registers)
    h8 yacc[UMAX];   // packed y accumulator

    const _Float16 w9h = (_Float16)wv[9];

    // Stage x as fp16 (zeros left of t=0); init lw = x, y = w9*x.
    // Right side needs no guard: un < NU  =>  t+7 <= tile*TILE + 8191 < L.
#pragma unroll
    for (int u = 0; u < UMAX; ++u) {
        yacc[u] = sp8((_Float16)0.f);
        const int un = tid + u * BLK;
        if (un < NU) {
            const int p = 8 * un;
            const int t = t0 + p;
            float4 xa = make_float4(0.f, 0.f, 0.f, 0.f);
            float4 xb = make_float4(0.f, 0.f, 0.f, 0.f);
            if (t >= 0) { xa = ld4f(&x[row + t]); xb = ld4f(&x[row + t + 4]); }
            h8 hv;
            hv[0] = (_Float16)xa.x; hv[1] = (_Float16)xa.y;
            hv[2] = (_Float16)xa.z; hv[3] = (_Float16)xa.w;
            hv[4] = (_Float16)xb.x; hv[5] = (_Float16)xb.y;
            hv[6] = (_Float16)xb.z; hv[7] = (_Float16)xb.w;
            st8(&buf[p], hv);
            lw[u] = hv;
            if (un >= HALO_U) yacc[u] = sp8(w9h) * hv;
        }
    }
    __syncthreads();

#define LEVEL_STEP(D, SU, WI)                                                  \
    level_compute<D, SU, false>(buf, h0v, h1v, WI, 0.f, lw, yacc, tid);        \
    __syncthreads();                                                           \
    publish<SU>(buf, lw, tid);                                                 \
    __syncthreads();

    LEVEL_STEP(1,   1,  wv[8])
    LEVEL_STEP(2,   2,  wv[7])
    LEVEL_STEP(4,   4,  wv[6])
    LEVEL_STEP(8,   7,  wv[5])
    LEVEL_STEP(16,  13, wv[4])
    LEVEL_STEP(32,  25, wv[3])
    LEVEL_STEP(64,  49, wv[2])
#undef LEVEL_STEP
    level_compute<128, 97, true>(buf, h0v, h1v, wv[1], wv[0], lw, yacc, tid);

    // Epilogue: unpack to fp32, GELU, two float4 stores per unit.
#pragma unroll
    for (int u = 0; u < UMAX; ++u) {
        const int un = tid + u * BLK;
        if (un >= HALO_U && un < NU) {
            const int p = 8 * un;
            const h8 v = yacc[u];
            float4 oa, ob;
            oa.x = gelu_f((float)v[0]); oa.y = gelu_f((float)v[1]);
            oa.z = gelu_f((float)v[2]); oa.w = gelu_f((float)v[3]);
            ob.x = gelu_f((float)v[4]); ob.y = gelu_f((float)v[5]);
            ob.z = gelu_f((float)v[6]); ob.w = gelu_f((float)v[7]);
            st4f(&out[row + t0 + p], oa);
            st4f(&out[row + t0 + p + 4], ob);
        }
    }
}

}  // namespace

extern "C" void kernel_launch(void* const* d_in, const int* in_sizes, int n_in,
                              void* d_out, int out_size, void* d_ws, size_t ws_size,
                              hipStream_t stream)
{
    const float* x  = (const float*)d_in[0];
    const float* h0 = (const float*)d_in[1];
    const float* h1 = (const float*)d_in[2];
    const float* w  = (const float*)d_in[3];
    float* out = (float*)d_out;

    const int nblocks = (out_size / L_) * NT;   // B*C*NT = 2048 = 8 blocks/CU exactly
    cmrc_kernel<<<nblocks, BLK, 0, stream>>>(x, h0, h1, w, out);
}

// Round 10
// 43.262 us; speedup vs baseline: 1.0646x; 1.0646x over previous
//
#include <hip/hip_runtime.h>
#include <cmath>

namespace {

typedef _Float16 h8 __attribute__((ext_vector_type(8)));

constexpr int C_     = 64;
constexpr int L_     = 32768;
constexpr int TILE   = 4096;
constexpr int HALO   = 776;           // receptive field 765, rounded to unit-8
constexpr int NB     = TILE + HALO;   // 4872 halfs
constexpr int NU     = NB / 8;        // 609 h8 units
constexpr int HALO_U = HALO / 8;      // 97
constexpr int NT     = L_ / TILE;     // 8 tiles per row
constexpr int BLK    = 256;
constexpr int UMAX   = (NU + BLK - 1) / BLK;   // 3 unit-slots per thread

__device__ __forceinline__ h8 ld8(const _Float16* p) { return *reinterpret_cast<const h8*>(p); }
__device__ __forceinline__ void st8(_Float16* p, h8 v) { *reinterpret_cast<h8*>(p) = v; }
__device__ __forceinline__ float4 ld4f(const float* p) { return *reinterpret_cast<const float4*>(p); }
__device__ __forceinline__ void st4f(float* p, float4 v) { *reinterpret_cast<float4*>(p) = v; }
__device__ __forceinline__ h8 sp8(_Float16 v) { return (h8){v,v,v,v,v,v,v,v}; }

// Guaranteed packed-FMA: the naive  acc += a*T0 + b*T1 + c*T2 + d*T3  sum tree
// only partially contracts (pk_mul + pk_add pairs). elementwise_fma forces
// v_pk_fma_f16 — exactly 4 FMAs per 4-tap dot (r10 theory: ~2x VALU bloat).
__device__ __forceinline__ h8 fma8(h8 a, h8 b, h8 c) {
    return __builtin_elementwise_fma(a, b, c);
}

template<int K>
__device__ __forceinline__ h8 shconc(h8 A, h8 B) {
    return __builtin_shufflevector(A, B, K, K+1, K+2, K+3, K+4, K+5, K+6, K+7);
}

// tanh-form GELU: v * sigmoid(1.5958*v + 0.07135*v^3); absmax-verified vs erf
// across six rounds (identical 0.0078125 overall absmax).
__device__ __forceinline__ float gelu_f(float v) {
    const float z = v * (1.5957691216057308f + 0.0713548162726f * v * v);
    const float e = __expf(-z);
    return v * __builtin_amdgcn_rcpf(1.0f + e);
}

// One level, dilation D. T3 = own unit (registers); T0..T2 from LDS.
// Frontier recursion (correctness-proven r3..r9): STARTU per level
// 1,2,4,7,13,25,49,97; valid unit g at level D reads down to g-3D/8 >= prev
// STARTU, so below-frontier garbage is never read. Guards kept per-slot: they
// bound live ranges (r4-r7: unguarded variants -> 188 VGPR or demotion).
template<int D, int STARTU, bool LAST>
__device__ __forceinline__ void level_pass(const _Float16* __restrict__ src,
                                           _Float16* __restrict__ dst,
                                           const float* h0f, const float* h1f,
                                           float wi, float w0,
                                           h8* lw, h8* yacc, int tid)
{
    _Float16 c1[4], c0[4];
#pragma unroll
    for (int t = 0; t < 4; ++t) {
        c1[t] = (_Float16)(wi * h1f[t]);
        c0[t] = (_Float16)(LAST ? w0 * h0f[t] : h0f[t]);
    }

#pragma unroll
    for (int u = 0; u < UMAX; ++u) {
        const int un = tid + u * BLK;
        if (un >= STARTU && un < NU) {
            const int p = 8 * un;
            const h8 T3 = lw[u];
            h8 T0, T1, T2;
            if constexpr (D == 1) {
                h8 Lv = ld8(&src[p - 8]);
                T0 = shconc<5>(Lv, T3);
                T1 = shconc<6>(Lv, T3);
                T2 = shconc<7>(Lv, T3);
            } else if constexpr (D == 2) {
                h8 Lv = ld8(&src[p - 8]);
                T0 = shconc<2>(Lv, T3);
                T1 = shconc<4>(Lv, T3);
                T2 = shconc<6>(Lv, T3);
            } else if constexpr (D == 4) {
                h8 Lv  = ld8(&src[p - 8]);
                h8 LL  = ld8(&src[p - 16]);
                T0 = shconc<4>(LL, Lv);
                T1 = Lv;
                T2 = shconc<4>(Lv, T3);
            } else {
                T0 = ld8(&src[p - 3 * D]);
                T1 = ld8(&src[p - 2 * D]);
                T2 = ld8(&src[p - D]);
            }
            if (un >= HALO_U) {   // y only matters inside the output tile
                h8 yv = yacc[u];
                yv = fma8(sp8(c1[0]), T0, yv);
                yv = fma8(sp8(c1[1]), T1, yv);
                yv = fma8(sp8(c1[2]), T2, yv);
                yv = fma8(sp8(c1[3]), T3, yv);
                yacc[u] = yv;
            }
            h8 nl = sp8(c0[0]) * T0;
            nl = fma8(sp8(c0[1]), T1, nl);
            nl = fma8(sp8(c0[2]), T2, nl);
            nl = fma8(sp8(c0[3]), T3, nl);
            if constexpr (LAST) {
                yacc[u] += nl;          // c0 already folded with w0
            } else {
                lw[u] = nl;
                st8(&dst[p], nl);
            }
        }
    }
}

// min-waves=8 (VGPR cap 64): guarded structure measured 28 VGPR — 2.3x
// headroom. LDS 2x9744B -> 8 blocks/CU.
__global__ __launch_bounds__(BLK, 8)
void cmrc_kernel(const float* __restrict__ x,
                 const float* __restrict__ h0,
                 const float* __restrict__ h1,
                 const float* __restrict__ w,
                 float* __restrict__ out)
{
    __shared__ alignas(16) _Float16 buf[2][NB];

    const int tid  = threadIdx.x;
    const int blk  = blockIdx.x;
    const int tile = blk % NT;
    const int bc   = blk / NT;            // b*C + c
    const int c    = bc % C_;
    const long row = (long)bc * L_;
    const int  t0  = tile * TILE - HALO;  // global pos of buffer p=0

    float h0v[4], h1v[4];
#pragma unroll
    for (int k = 0; k < 4; ++k) { h0v[k] = h0[c*4+k]; h1v[k] = h1[c*4+k]; }
    float wv[10];
#pragma unroll
    for (int i = 0; i < 10; ++i) wv[i] = w[c*10+i];

    h8 lw[UMAX];     // running low residual (own units, registers)
    h8 yacc[UMAX];   // packed y accumulator

    const _Float16 w9h = (_Float16)wv[9];

    // Stage x as fp16 (zeros left of t=0); init lw = x, y = w9*x.
#pragma unroll
    for (int u = 0; u < UMAX; ++u) {
        yacc[u] = sp8((_Float16)0.f);
        const int un = tid + u * BLK;
        if (un < NU) {
            const int p = 8 * un;
            const int t = t0 + p;
            float4 xa = make_float4(0.f, 0.f, 0.f, 0.f);
            float4 xb = make_float4(0.f, 0.f, 0.f, 0.f);
            if (t >= 0)     xa = ld4f(&x[row + t]);
            if (t + 4 >= 0) xb = ld4f(&x[row + t + 4]);
            h8 hv;
            hv[0] = (_Float16)xa.x; hv[1] = (_Float16)xa.y;
            hv[2] = (_Float16)xa.z; hv[3] = (_Float16)xa.w;
            hv[4] = (_Float16)xb.x; hv[5] = (_Float16)xb.y;
            hv[6] = (_Float16)xb.z; hv[7] = (_Float16)xb.w;
            st8(&buf[0][p], hv);
            lw[u] = hv;
            if (un >= HALO_U) yacc[u] = sp8(w9h) * hv;
        }
    }
    __syncthreads();

    level_pass<1,   1,  false>(buf[0], buf[1], h0v, h1v, wv[8], 0.f, lw, yacc, tid); __syncthreads();
    level_pass<2,   2,  false>(buf[1], buf[0], h0v, h1v, wv[7], 0.f, lw, yacc, tid); __syncthreads();
    level_pass<4,   4,  false>(buf[0], buf[1], h0v, h1v, wv[6], 0.f, lw, yacc, tid); __syncthreads();
    level_pass<8,   7,  false>(buf[1], buf[0], h0v, h1v, wv[5], 0.f, lw, yacc, tid); __syncthreads();
    level_pass<16,  13, false>(buf[0], buf[1], h0v, h1v, wv[4], 0.f, lw, yacc, tid); __syncthreads();
    level_pass<32,  25, false>(buf[1], buf[0], h0v, h1v, wv[3], 0.f, lw, yacc, tid); __syncthreads();
    level_pass<64,  49, false>(buf[0], buf[1], h0v, h1v, wv[2], 0.f, lw, yacc, tid); __syncthreads();
    level_pass<128, 97, true >(buf[1], buf[0], h0v, h1v, wv[1], wv[0], lw, yacc, tid);

    // Epilogue: unpack to fp32, GELU, two float4 stores per unit.
#pragma unroll
    for (int u = 0; u < UMAX; ++u) {
        const int un = tid + u * BLK;
        if (un >= HALO_U && un < NU) {
            const int p = 8 * un;
            const h8 v = yacc[u];
            float4 oa, ob;
            oa.x = gelu_f((float)v[0]); oa.y = gelu_f((float)v[1]);
            oa.z = gelu_f((float)v[2]); oa.w = gelu_f((float)v[3]);
            ob.x = gelu_f((float)v[4]); ob.y = gelu_f((float)v[5]);
            ob.z = gelu_f((float)v[6]); ob.w = gelu_f((float)v[7]);
            st4f(&out[row + t0 + p], oa);
            st4f(&out[row + t0 + p + 4], ob);
        }
    }
}

}  // namespace

extern "C" void kernel_launch(void* const* d_in, const int* in_sizes, int n_in,
                              void* d_out, int out_size, void* d_ws, size_t ws_size,
                              hipStream_t stream)
{
    const float* x  = (const float*)d_in[0];
    const float* h0 = (const float*)d_in[1];
    const float* h1 = (const float*)d_in[2];
    const float* w  = (const float*)d_in[3];
    float* out = (float*)d_out;

    const int nblocks = (out_size / L_) * NT;   // B*C*NT = 4096
    cmrc_kernel<<<nblocks, BLK, 0, stream>>>(x, h0, h1, w, out);
}